// Round 1
// baseline (798.788 us; speedup 1.0000x reference)
//
#include <hip/hip_runtime.h>

#define NN 50000
#define TT 24
#define HH 64
#define HORZ 12
#define EE 1600000
#define NPB 98  // (NN+511)/512 scan blocks

typedef __attribute__((ext_vector_type(8))) short bf16x8;
typedef __attribute__((ext_vector_type(4))) float f32x4;

__device__ __forceinline__ unsigned short f2bf(float f) {
  unsigned int u = __float_as_uint(f);
  unsigned int r = u + 0x7fffu + ((u >> 16) & 1u);
  return (unsigned short)(r >> 16);
}
__device__ __forceinline__ float bf2f(unsigned short b) {
  return __uint_as_float(((unsigned int)b) << 16);
}

// ---------- build W_hh MFMA B-fragments (hi/lo split) ----------
// layout: [part(hi=0,lo=1)][nf(12)][kf(2)][lane(64)][8]  (bf16 bits as ushort)
// B[k][n] = w_hh[gate = 16*nf + (lane&15)][k = 32*kf + 8*(lane>>4) + j]
__global__ void build_wfrag_kernel(const float* __restrict__ w_hh,
                                   unsigned short* __restrict__ wfrag) {
  int idx = blockIdx.x * 256 + threadIdx.x;
  if (idx >= 12 * 2 * 64 * 8) return;
  int j = idx & 7;
  int l = (idx >> 3) & 63;
  int kf = (idx >> 9) & 1;
  int nf = idx >> 10;
  int gate = 16 * nf + (l & 15);
  int k = 32 * kf + 8 * (l >> 4) + j;
  float v = w_hh[gate * 64 + k];
  unsigned short hi = f2bf(v);
  unsigned short lo = f2bf(v - bf2f(hi));
  wfrag[idx] = hi;
  wfrag[12288 + idx] = lo;
}

// ---------- persistent MFMA GRU: block = 4 waves = 64 nodes ----------
__global__ __launch_bounds__(256) void gru_kernel(
    const float* __restrict__ x, const float* __restrict__ w_ih,
    const float* __restrict__ b_ih, const float* __restrict__ b_hh,
    const unsigned short* __restrict__ wfrag, float* __restrict__ hout) {
  __shared__ __align__(16) unsigned short wf[24576];      // 48 KB W frags hi+lo
  __shared__ __align__(16) unsigned short shi[4][16][72]; // h hi, row stride 144B (16B mult)
  __shared__ __align__(16) unsigned short slo[4][16][72]; // h lo
  __shared__ float xs[64 * TT];

  int tid = threadIdx.x;
  {
    const float4* s4 = (const float4*)wfrag;
    float4* d4 = (float4*)wf;
    for (int i = tid; i < 3072; i += 256) d4[i] = s4[i];
  }
  int base = blockIdx.x * 64;
  for (int i = tid; i < 64 * TT; i += 256) {
    int gi = base * TT + i;
    xs[i] = (gi < NN * TT) ? x[gi] : 0.f;
  }
  __syncthreads();

  const int lane = tid & 63;
  const int w = tid >> 6;
  const int c = lane & 15;   // D col / A row (node within... A row = node; D col = gate)
  const int hq = lane >> 4;  // quarter

  // per-lane gate constants, d = c + 16*g
  float wir[4], wiz[4], win[4], bir[4], biz[4], bin[4], bhr[4], bhz[4], bhn[4];
#pragma unroll
  for (int g = 0; g < 4; ++g) {
    int d = c + 16 * g;
    wir[g] = w_ih[d]; wiz[g] = w_ih[64 + d]; win[g] = w_ih[128 + d];
    bir[g] = b_ih[d]; biz[g] = b_ih[64 + d]; bin[g] = b_ih[128 + d];
    bhr[g] = b_hh[d]; bhz[g] = b_hh[64 + d]; bhn[g] = b_hh[128 + d];
  }

  float hreg[4][4];  // [r][g] fp32 h-state in D layout: node=(hq*4+r), dim=c+16g
#pragma unroll
  for (int r = 0; r < 4; ++r)
#pragma unroll
    for (int g = 0; g < 4; ++g) hreg[r][g] = 0.f;

  for (int t = 0; t < TT; ++t) {
    f32x4 acc[12];  // gh accumulators, init with b_hh (broadcast per column)
#pragma unroll
    for (int g = 0; g < 4; ++g) {
#pragma unroll
      for (int r = 0; r < 4; ++r) {
        acc[g][r] = bhr[g];
        acc[4 + g][r] = bhz[g];
        acc[8 + g][r] = bhn[g];
      }
    }
    if (t > 0) {
      bf16x8 ahi[2], alo[2];
#pragma unroll
      for (int kf = 0; kf < 2; ++kf) {
        ahi[kf] = *(const bf16x8*)&shi[w][c][32 * kf + 8 * hq];
        alo[kf] = *(const bf16x8*)&slo[w][c][32 * kf + 8 * hq];
      }
#pragma unroll
      for (int nf = 0; nf < 12; ++nf) {
#pragma unroll
        for (int kf = 0; kf < 2; ++kf) {
          bf16x8 bh = *(const bf16x8*)&wf[((nf * 2 + kf) * 64 + lane) * 8];
          bf16x8 bl = *(const bf16x8*)&wf[12288 + ((nf * 2 + kf) * 64 + lane) * 8];
          acc[nf] = __builtin_amdgcn_mfma_f32_16x16x32_bf16(ahi[kf], bh, acc[nf], 0, 0, 0);
          acc[nf] = __builtin_amdgcn_mfma_f32_16x16x32_bf16(alo[kf], bh, acc[nf], 0, 0, 0);
          acc[nf] = __builtin_amdgcn_mfma_f32_16x16x32_bf16(ahi[kf], bl, acc[nf], 0, 0, 0);
        }
      }
    }
    // elementwise gates; D layout: row(node)=4*hq+r, col(dim)=c+16g
#pragma unroll
    for (int r = 0; r < 4; ++r) {
      int m = 4 * hq + r;
      float xt = xs[(w * 16 + m) * TT + t];
#pragma unroll
      for (int g = 0; g < 4; ++g) {
        float rg = 1.f / (1.f + __expf(-(xt * wir[g] + bir[g] + acc[g][r])));
        float zg = 1.f / (1.f + __expf(-(xt * wiz[g] + biz[g] + acc[4 + g][r])));
        float e2 = __expf(2.f * (xt * win[g] + bin[g] + rg * acc[8 + g][r]));
        float nn = (e2 - 1.f) / (e2 + 1.f);
        float hn = (1.f - zg) * nn + zg * hreg[r][g];
        hreg[r][g] = hn;
        unsigned short hb = f2bf(hn);
        shi[w][m][c + 16 * g] = hb;
        slo[w][m][c + 16 * g] = f2bf(hn - bf2f(hb));
      }
    }
    __syncthreads();  // writes of step t visible before A-frag reads of t+1
  }

  int n0 = base + w * 16;
#pragma unroll
  for (int r = 0; r < 4; ++r) {
    int n = n0 + 4 * hq + r;
    if (n < NN) {
#pragma unroll
      for (int g = 0; g < 4; ++g) hout[n * 64 + c + 16 * g] = hreg[r][g];
    }
  }
}

// ---------- degree histogram ----------
__global__ void count_kernel(const int* __restrict__ dst, int* __restrict__ cnt) {
  int i = blockIdx.x * 256 + threadIdx.x;
  if (i < EE) atomicAdd(&cnt[dst[i]], 1);
}

__global__ void dinv_kernel(const int* __restrict__ cnt, float* __restrict__ dinv) {
  int i = blockIdx.x * 256 + threadIdx.x;
  if (i < NN) dinv[i] = rsqrtf((float)(cnt[i] + 1));  // +1 self loop
}

// ---------- scan (3-phase) for CSR row offsets ----------
__global__ void scan1_kernel(const int* __restrict__ cnt, int* __restrict__ part) {
  __shared__ int s[512];
  int i = blockIdx.x * 512 + threadIdx.x;
  s[threadIdx.x] = (i < NN) ? cnt[i] : 0;
  __syncthreads();
  for (int off = 256; off > 0; off >>= 1) {
    if (threadIdx.x < off) s[threadIdx.x] += s[threadIdx.x + off];
    __syncthreads();
  }
  if (threadIdx.x == 0) part[blockIdx.x] = s[0];
}

__global__ void scan2_kernel(int* __restrict__ part) {
  if (threadIdx.x == 0) {
    int a = 0;
    for (int b = 0; b < NPB; ++b) { int v = part[b]; part[b] = a; a += v; }
  }
}

__global__ void scan3_kernel(const int* __restrict__ cnt, const int* __restrict__ part,
                             int* __restrict__ row_start, int* __restrict__ cursor) {
  __shared__ int s[2][512];
  int tid = threadIdx.x;
  int i = blockIdx.x * 512 + tid;
  int v = (i < NN) ? cnt[i] : 0;
  s[0][tid] = v;
  __syncthreads();
  int cur = 0;
  for (int off = 1; off < 512; off <<= 1) {
    int nxt = cur ^ 1;
    int val = s[cur][tid] + ((tid >= off) ? s[cur][tid - off] : 0);
    s[nxt][tid] = val;
    __syncthreads();
    cur = nxt;
  }
  int excl = s[cur][tid] - v;
  if (i < NN) {
    int rs = part[blockIdx.x] + excl;
    row_start[i] = rs;
    cursor[i] = rs;
  }
  if (i == 0) row_start[NN] = EE;
}

__global__ void scatter_kernel(const int* __restrict__ src, const int* __restrict__ dst,
                               int* __restrict__ cursor, int* __restrict__ csr_src) {
  int i = blockIdx.x * 256 + threadIdx.x;
  if (i < EE) {
    int p = atomicAdd(&cursor[dst[i]], 1);
    csr_src[p] = src[i];
  }
}

// ---------- h @ W^T (64x64) ----------
__global__ __launch_bounds__(256) void linear64_kernel(
    const float* __restrict__ hin, const float* __restrict__ W, float* __restrict__ outw) {
  __shared__ float sW[4096];
  for (int i = threadIdx.x; i < 4096; i += 256) sW[i] = W[i];
  __syncthreads();
  int n = blockIdx.x * 256 + threadIdx.x;
  if (n >= NN) return;
  float h[64];
  const float4* hp = (const float4*)(hin + n * 64);
#pragma unroll
  for (int i = 0; i < 16; ++i) {
    float4 v = hp[i];
    h[4 * i] = v.x; h[4 * i + 1] = v.y; h[4 * i + 2] = v.z; h[4 * i + 3] = v.w;
  }
  for (int o = 0; o < 64; o += 4) {
    float a0 = 0.f, a1 = 0.f, a2 = 0.f, a3 = 0.f;
#pragma unroll
    for (int k = 0; k < 64; ++k) {
      float hk = h[k];
      a0 += hk * sW[(o + 0) * 64 + k];
      a1 += hk * sW[(o + 1) * 64 + k];
      a2 += hk * sW[(o + 2) * 64 + k];
      a3 += hk * sW[(o + 3) * 64 + k];
    }
    *(float4*)&outw[n * 64 + o] = make_float4(a0, a1, a2, a3);
  }
}

// ---------- CSR aggregation + self-loop + bias + relu; wave per node ----------
__global__ __launch_bounds__(256) void agg_kernel(
    const float* __restrict__ hw, const float* __restrict__ dinv,
    const int* __restrict__ row_start, const int* __restrict__ csr_src,
    const float* __restrict__ bias, float* __restrict__ out) {
  int wid = blockIdx.x * 4 + (threadIdx.x >> 6);
  int lane = threadIdx.x & 63;
  if (wid >= NN) return;
  float dn = dinv[wid];
  float acc = hw[wid * 64 + lane] * dn * dn;  // self loop
  int e0 = row_start[wid], e1 = row_start[wid + 1];
  for (int e = e0; e < e1; ++e) {
    int s = csr_src[e];
    acc += dinv[s] * dn * hw[s * 64 + lane];
  }
  float v = acc + bias[lane];
  out[wid * 64 + lane] = v > 0.f ? v : 0.f;
}

// ---------- final FC (64 -> 12) ----------
__global__ __launch_bounds__(256) void fc_kernel(
    const float* __restrict__ hin, const float* __restrict__ W,
    const float* __restrict__ b, float* __restrict__ out) {
  __shared__ float sW[HORZ * 64];
  __shared__ float sb[HORZ];
  for (int i = threadIdx.x; i < HORZ * 64; i += 256) sW[i] = W[i];
  if (threadIdx.x < HORZ) sb[threadIdx.x] = b[threadIdx.x];
  __syncthreads();
  int n = blockIdx.x * 256 + threadIdx.x;
  if (n >= NN) return;
  float h[64];
  const float4* hp = (const float4*)(hin + n * 64);
#pragma unroll
  for (int i = 0; i < 16; ++i) {
    float4 v = hp[i];
    h[4 * i] = v.x; h[4 * i + 1] = v.y; h[4 * i + 2] = v.z; h[4 * i + 3] = v.w;
  }
  float a[HORZ];
#pragma unroll
  for (int o = 0; o < HORZ; ++o) a[o] = sb[o];
#pragma unroll
  for (int k = 0; k < 64; ++k) {
    float hk = h[k];
#pragma unroll
    for (int o = 0; o < HORZ; ++o) a[o] += hk * sW[o * 64 + k];
  }
#pragma unroll
  for (int o = 0; o < HORZ; ++o) out[n * HORZ + o] = a[o];
}

extern "C" void kernel_launch(void* const* d_in, const int* in_sizes, int n_in,
                              void* d_out, int out_size, void* d_ws, size_t ws_size,
                              hipStream_t stream) {
  (void)in_sizes; (void)n_in; (void)out_size; (void)ws_size;
  const float* x = (const float*)d_in[0];
  const int* edge_index = (const int*)d_in[1];
  const float* w_ih = (const float*)d_in[2];
  const float* w_hh = (const float*)d_in[3];
  const float* b_ih = (const float*)d_in[4];
  const float* b_hh = (const float*)d_in[5];
  const float* gc1_w = (const float*)d_in[6];
  const float* gc1_b = (const float*)d_in[7];
  const float* gc2_w = (const float*)d_in[8];
  const float* gc2_b = (const float*)d_in[9];
  const float* fc_w = (const float*)d_in[10];
  const float* fc_b = (const float*)d_in[11];
  float* out = (float*)d_out;

  // workspace layout (wfrag first for 16B alignment of float arrays after it)
  char* ws = (char*)d_ws;
  unsigned short* wfrag = (unsigned short*)ws;        // 24576 ushort = 49152 B
  float* hbuf = (float*)(ws + 49152);                 // NN*64
  float* hw = hbuf + NN * 64;                         // NN*64
  float* dinv = hw + NN * 64;                         // NN
  int* cnt = (int*)(dinv + NN);                       // NN
  int* row_start = cnt + NN;                          // NN+1
  int* cursor = row_start + NN + 1;                   // NN
  int* csr_src = cursor + NN;                         // EE
  int* part = csr_src + EE;                           // 128

  const int* esrc = edge_index;
  const int* edst = edge_index + EE;

  hipMemsetAsync(cnt, 0, NN * sizeof(int), stream);
  build_wfrag_kernel<<<48, 256, 0, stream>>>(w_hh, wfrag);
  gru_kernel<<<(NN + 63) / 64, 256, 0, stream>>>(x, w_ih, b_ih, b_hh, wfrag, hbuf);
  count_kernel<<<(EE + 255) / 256, 256, 0, stream>>>(edst, cnt);
  dinv_kernel<<<(NN + 255) / 256, 256, 0, stream>>>(cnt, dinv);
  scan1_kernel<<<NPB, 512, 0, stream>>>(cnt, part);
  scan2_kernel<<<1, 64, 0, stream>>>(part);
  scan3_kernel<<<NPB, 512, 0, stream>>>(cnt, part, row_start, cursor);
  scatter_kernel<<<(EE + 255) / 256, 256, 0, stream>>>(esrc, edst, cursor, csr_src);

  linear64_kernel<<<(NN + 255) / 256, 256, 0, stream>>>(hbuf, gc1_w, hw);
  agg_kernel<<<(NN + 3) / 4, 256, 0, stream>>>(hw, dinv, row_start, csr_src, gc1_b, hbuf);
  linear64_kernel<<<(NN + 255) / 256, 256, 0, stream>>>(hbuf, gc2_w, hw);
  agg_kernel<<<(NN + 3) / 4, 256, 0, stream>>>(hw, dinv, row_start, csr_src, gc2_b, hbuf);
  fc_kernel<<<(NN + 255) / 256, 256, 0, stream>>>(hbuf, fc_w, fc_b, out);
}

// Round 2
// 477.032 us; speedup vs baseline: 1.6745x; 1.6745x over previous
//
#include <hip/hip_runtime.h>

#define NN 50000
#define TT 24
#define HH 64
#define HORZ 12
#define EE 1600000
#define NPB 98  // (NN+511)/512 scan blocks

typedef __attribute__((ext_vector_type(8))) _Float16 f16x8;
typedef __attribute__((ext_vector_type(4))) float f32x4;

__device__ __forceinline__ float sigm(float x) {
  return __builtin_amdgcn_rcpf(1.f + __expf(-x));
}
__device__ __forceinline__ float tanh_f(float x) {
  return 1.f - 2.f * __builtin_amdgcn_rcpf(1.f + __expf(2.f * x));
}

// ---------- build fp16 MFMA B-fragments for a [rows x 64] weight (out = h @ W^T) ----------
// layout: [nf][kf(2)][lane(64)][8];  B[k][col] = W[col][k], col = 16*nf + (l&15), k = 32*kf + 8*(l>>4) + j
__global__ void build_frag_kernel(const float* __restrict__ W, _Float16* __restrict__ frag,
                                  int rows, int nfr) {
  int idx = blockIdx.x * 256 + threadIdx.x;
  if (idx >= nfr * 1024) return;
  int j = idx & 7;
  int l = (idx >> 3) & 63;
  int kf = (idx >> 9) & 1;
  int nf = idx >> 10;
  int col = 16 * nf + (l & 15);
  int k = 32 * kf + 8 * (l >> 4) + j;
  frag[idx] = (col < rows) ? (_Float16)W[col * 64 + k] : (_Float16)0.f;
}

// ---------- persistent MFMA GRU: block = 16 waves = 256 nodes, no per-step barrier ----------
__global__ __launch_bounds__(1024) void gru_kernel(
    const float* __restrict__ x, const float* __restrict__ w_ih,
    const float* __restrict__ b_ih, const float* __restrict__ b_hh,
    const _Float16* __restrict__ wfrag, float* __restrict__ hout) {
  __shared__ __align__(16) _Float16 wf[12288];       // 24 KB: [nf(12)][kf(2)][lane][8]
  __shared__ __align__(16) _Float16 sh[16][16][72];  // 36.9 KB: per-wave h bounce, 144B row stride
  __shared__ float xs[256 * TT];                     // 24.6 KB

  int tid = threadIdx.x;
  {
    const float4* s4 = (const float4*)wfrag;
    float4* d4 = (float4*)wf;
    for (int i = tid; i < 1536; i += 1024) d4[i] = s4[i];
  }
  int base = blockIdx.x * 256;
  for (int i = tid; i < 256 * TT; i += 1024) {
    int gi = base * TT + i;
    xs[i] = (gi < NN * TT) ? x[gi] : 0.f;
  }
  __syncthreads();

  const int lane = tid & 63;
  const int w = tid >> 6;    // wave 0..15, owns 16 nodes + sh[w]
  const int c = lane & 15;   // A row (node) for MFMA reads; D col (gate dim)
  const int q = lane >> 4;

  // per-lane gate constants for dims d = c + 16g
  float wir[4], wiz[4], win[4], arb[4], azb[4], bin[4], bhn[4];
#pragma unroll
  for (int g = 0; g < 4; ++g) {
    int d = c + 16 * g;
    wir[g] = w_ih[d]; wiz[g] = w_ih[64 + d]; win[g] = w_ih[128 + d];
    arb[g] = b_ih[d] + b_hh[d];
    azb[g] = b_ih[64 + d] + b_hh[64 + d];
    bin[g] = b_ih[128 + d];
    bhn[g] = b_hh[128 + d];
  }

  float hreg[4][4];  // fp32 h-state in D layout: node = 4q+r, dim = c+16g
#pragma unroll
  for (int r = 0; r < 4; ++r)
#pragma unroll
    for (int g = 0; g < 4; ++g) hreg[r][g] = 0.f;

#pragma unroll 1
  for (int t = 0; t < TT; ++t) {
    f32x4 acc[12];
#pragma unroll
    for (int g = 0; g < 4; ++g) {
      acc[g] = (f32x4){arb[g], arb[g], arb[g], arb[g]};
      acc[4 + g] = (f32x4){azb[g], azb[g], azb[g], azb[g]};
      acc[8 + g] = (f32x4){bhn[g], bhn[g], bhn[g], bhn[g]};
    }
    if (t > 0) {
      f16x8 a0 = *(const f16x8*)&sh[w][c][0 + 8 * q];
      f16x8 a1 = *(const f16x8*)&sh[w][c][32 + 8 * q];
#pragma unroll
      for (int nf = 0; nf < 12; ++nf) {
        f16x8 b0 = *(const f16x8*)&wf[((nf * 2 + 0) * 64 + lane) * 8];
        acc[nf] = __builtin_amdgcn_mfma_f32_16x16x32_f16(a0, b0, acc[nf], 0, 0, 0);
      }
#pragma unroll
      for (int nf = 0; nf < 12; ++nf) {
        f16x8 b1 = *(const f16x8*)&wf[((nf * 2 + 1) * 64 + lane) * 8];
        acc[nf] = __builtin_amdgcn_mfma_f32_16x16x32_f16(a1, b1, acc[nf], 0, 0, 0);
      }
    }
    // gates; D layout: row(node) = 4q+r, col(dim) = c+16g
#pragma unroll
    for (int r = 0; r < 4; ++r) {
      int m = 4 * q + r;
      float xt = xs[(w * 16 + m) * TT + t];
#pragma unroll
      for (int g = 0; g < 4; ++g) {
        float rg = sigm(xt * wir[g] + acc[g][r]);
        float zg = sigm(xt * wiz[g] + acc[4 + g][r]);
        float nn = tanh_f(rg * acc[8 + g][r] + (xt * win[g] + bin[g]));
        float hn = nn + zg * (hreg[r][g] - nn);
        hreg[r][g] = hn;
        sh[w][m][c + 16 * g] = (_Float16)hn;
      }
    }
    // no __syncthreads: sh[w] is wave-private; lgkmcnt ordering is compiler-enforced
  }

  int n0 = base + w * 16;
#pragma unroll
  for (int r = 0; r < 4; ++r) {
    int n = n0 + 4 * q + r;
    if (n < NN) {
#pragma unroll
      for (int g = 0; g < 4; ++g) hout[n * 64 + c + 16 * g] = hreg[r][g];
    }
  }
}

// ---------- degree histogram (int4) ----------
__global__ void count_kernel(const int* __restrict__ dst, int* __restrict__ cnt) {
  int i = blockIdx.x * 256 + threadIdx.x;
  int b = i * 4;
  if (b + 3 < EE) {
    int4 d = *(const int4*)&dst[b];
    atomicAdd(&cnt[d.x], 1);
    atomicAdd(&cnt[d.y], 1);
    atomicAdd(&cnt[d.z], 1);
    atomicAdd(&cnt[d.w], 1);
  } else {
    for (int k = b; k < EE; ++k) atomicAdd(&cnt[dst[k]], 1);
  }
}

__global__ void dinv_kernel(const int* __restrict__ cnt, float* __restrict__ dinv) {
  int i = blockIdx.x * 256 + threadIdx.x;
  if (i < NN) dinv[i] = rsqrtf((float)(cnt[i] + 1));  // +1 self loop
}

// ---------- scan (3-phase) for CSR row offsets ----------
__global__ void scan1_kernel(const int* __restrict__ cnt, int* __restrict__ part) {
  __shared__ int s[512];
  int i = blockIdx.x * 512 + threadIdx.x;
  s[threadIdx.x] = (i < NN) ? cnt[i] : 0;
  __syncthreads();
  for (int off = 256; off > 0; off >>= 1) {
    if (threadIdx.x < off) s[threadIdx.x] += s[threadIdx.x + off];
    __syncthreads();
  }
  if (threadIdx.x == 0) part[blockIdx.x] = s[0];
}

__global__ void scan2_kernel(int* __restrict__ part) {
  __shared__ int s[128];
  int t = threadIdx.x;
  int v = (t < NPB) ? part[t] : 0;
  s[t] = v;
  __syncthreads();
  for (int off = 1; off < 128; off <<= 1) {
    int a = s[t];
    int b = (t >= off) ? s[t - off] : 0;
    __syncthreads();
    s[t] = a + b;
    __syncthreads();
  }
  if (t < NPB) part[t] = s[t] - v;  // exclusive
}

__global__ void scan3_kernel(const int* __restrict__ cnt, const int* __restrict__ part,
                             int* __restrict__ row_start, int* __restrict__ cursor) {
  __shared__ int s[2][512];
  int tid = threadIdx.x;
  int i = blockIdx.x * 512 + tid;
  int v = (i < NN) ? cnt[i] : 0;
  s[0][tid] = v;
  __syncthreads();
  int cur = 0;
  for (int off = 1; off < 512; off <<= 1) {
    int nxt = cur ^ 1;
    int val = s[cur][tid] + ((tid >= off) ? s[cur][tid - off] : 0);
    s[nxt][tid] = val;
    __syncthreads();
    cur = nxt;
  }
  int excl = s[cur][tid] - v;
  if (i < NN) {
    int rs = part[blockIdx.x] + excl;
    row_start[i] = rs;
    cursor[i] = rs;
  }
  if (i == 0) row_start[NN] = EE;
}

__global__ void scatter_kernel(const int* __restrict__ src, const int* __restrict__ dst,
                               int* __restrict__ cursor, int* __restrict__ csr_src) {
  int i = blockIdx.x * 256 + threadIdx.x;
  if (i < EE) {
    int p = atomicAdd(&cursor[dst[i]], 1);
    csr_src[p] = src[i];
  }
}

// ---------- MFMA linear: out[n] = dinv[n] * (h[n] @ W^T), 64->64 ----------
__global__ __launch_bounds__(256) void linear_mfma_kernel(
    const float* __restrict__ hin, const _Float16* __restrict__ frag,
    const float* __restrict__ dinv, float* __restrict__ out) {
  __shared__ __align__(16) _Float16 sf[4096];  // 8 KB
  int tid = threadIdx.x;
  {
    const float4* s4 = (const float4*)frag;
    float4* d4 = (float4*)sf;
    for (int i = tid; i < 512; i += 256) d4[i] = s4[i];
  }
  __syncthreads();
  const int lane = tid & 63;
  const int w = tid >> 6;
  const int c = lane & 15;
  const int q = lane >> 4;
  int n0 = blockIdx.x * 64 + w * 16;
  int nA = n0 + c;
  int nc = nA < NN ? nA : NN - 1;  // clamp; garbage rows are never stored
  const float* hp = hin + nc * 64;

  f16x8 a[2];
#pragma unroll
  for (int kf = 0; kf < 2; ++kf) {
    float4 u = *(const float4*)&hp[32 * kf + 8 * q];
    float4 v = *(const float4*)&hp[32 * kf + 8 * q + 4];
    a[kf][0] = (_Float16)u.x; a[kf][1] = (_Float16)u.y;
    a[kf][2] = (_Float16)u.z; a[kf][3] = (_Float16)u.w;
    a[kf][4] = (_Float16)v.x; a[kf][5] = (_Float16)v.y;
    a[kf][6] = (_Float16)v.z; a[kf][7] = (_Float16)v.w;
  }
  f32x4 acc[4];
#pragma unroll
  for (int nf = 0; nf < 4; ++nf) acc[nf] = (f32x4){0.f, 0.f, 0.f, 0.f};
#pragma unroll
  for (int kf = 0; kf < 2; ++kf) {
#pragma unroll
    for (int nf = 0; nf < 4; ++nf) {
      f16x8 b = *(const f16x8*)&sf[((nf * 2 + kf) * 64 + lane) * 8];
      acc[nf] = __builtin_amdgcn_mfma_f32_16x16x32_f16(a[kf], b, acc[nf], 0, 0, 0);
    }
  }
#pragma unroll
  for (int r = 0; r < 4; ++r) {
    int n = n0 + 4 * q + r;
    if (n < NN) {
      float dn = dinv[n];
#pragma unroll
      for (int nf = 0; nf < 4; ++nf) out[n * 64 + c + 16 * nf] = acc[nf][r] * dn;
    }
  }
}

// ---------- CSR aggregation (pre-scaled hw) + bias + relu; wave per node ----------
__global__ __launch_bounds__(256) void agg_kernel(
    const float* __restrict__ hwp, const float* __restrict__ dinv,
    const int* __restrict__ row_start, const int* __restrict__ csr_src,
    const float* __restrict__ bias, float* __restrict__ out) {
  int wid = blockIdx.x * 4 + (threadIdx.x >> 6);
  int lane = threadIdx.x & 63;
  if (wid >= NN) return;
  int e0 = row_start[wid], e1 = row_start[wid + 1];
  float a0 = hwp[wid * 64 + lane];  // self loop (already dinv-scaled)
  float a1 = 0.f, a2 = 0.f, a3 = 0.f;
  int e = e0;
  for (; e + 4 <= e1; e += 4) {
    int s0 = csr_src[e], s1 = csr_src[e + 1], s2 = csr_src[e + 2], s3 = csr_src[e + 3];
    a0 += hwp[s0 * 64 + lane];
    a1 += hwp[s1 * 64 + lane];
    a2 += hwp[s2 * 64 + lane];
    a3 += hwp[s3 * 64 + lane];
  }
  for (; e < e1; ++e) a0 += hwp[csr_src[e] * 64 + lane];
  float v = (a0 + a1 + a2 + a3) * dinv[wid] + bias[lane];
  out[wid * 64 + lane] = v > 0.f ? v : 0.f;
}

// ---------- MFMA final FC (64 -> 12, padded to 16) ----------
__global__ __launch_bounds__(256) void fc_mfma_kernel(
    const float* __restrict__ hin, const _Float16* __restrict__ frag,
    const float* __restrict__ bias, float* __restrict__ out) {
  __shared__ __align__(16) _Float16 sf[1024];  // 2 KB
  int tid = threadIdx.x;
  {
    const float4* s4 = (const float4*)frag;
    float4* d4 = (float4*)sf;
    if (tid < 128) d4[tid] = s4[tid];
  }
  __syncthreads();
  const int lane = tid & 63;
  const int w = tid >> 6;
  const int c = lane & 15;
  const int q = lane >> 4;
  int n0 = blockIdx.x * 64 + w * 16;
  int nA = n0 + c;
  int nc = nA < NN ? nA : NN - 1;
  const float* hp = hin + nc * 64;

  f16x8 a[2];
#pragma unroll
  for (int kf = 0; kf < 2; ++kf) {
    float4 u = *(const float4*)&hp[32 * kf + 8 * q];
    float4 v = *(const float4*)&hp[32 * kf + 8 * q + 4];
    a[kf][0] = (_Float16)u.x; a[kf][1] = (_Float16)u.y;
    a[kf][2] = (_Float16)u.z; a[kf][3] = (_Float16)u.w;
    a[kf][4] = (_Float16)v.x; a[kf][5] = (_Float16)v.y;
    a[kf][6] = (_Float16)v.z; a[kf][7] = (_Float16)v.w;
  }
  float bc = (c < HORZ) ? bias[c] : 0.f;
  f32x4 acc = (f32x4){bc, bc, bc, bc};
#pragma unroll
  for (int kf = 0; kf < 2; ++kf) {
    f16x8 b = *(const f16x8*)&sf[(kf * 64 + lane) * 8];
    acc = __builtin_amdgcn_mfma_f32_16x16x32_f16(a[kf], b, acc, 0, 0, 0);
  }
  if (c < HORZ) {
#pragma unroll
    for (int r = 0; r < 4; ++r) {
      int n = n0 + 4 * q + r;
      if (n < NN) out[n * HORZ + c] = acc[r];
    }
  }
}

extern "C" void kernel_launch(void* const* d_in, const int* in_sizes, int n_in,
                              void* d_out, int out_size, void* d_ws, size_t ws_size,
                              hipStream_t stream) {
  (void)in_sizes; (void)n_in; (void)out_size; (void)ws_size;
  const float* x = (const float*)d_in[0];
  const int* edge_index = (const int*)d_in[1];
  const float* w_ih = (const float*)d_in[2];
  const float* w_hh = (const float*)d_in[3];
  const float* b_ih = (const float*)d_in[4];
  const float* b_hh = (const float*)d_in[5];
  const float* gc1_w = (const float*)d_in[6];
  const float* gc1_b = (const float*)d_in[7];
  const float* gc2_w = (const float*)d_in[8];
  const float* gc2_b = (const float*)d_in[9];
  const float* fc_w = (const float*)d_in[10];
  const float* fc_b = (const float*)d_in[11];
  float* out = (float*)d_out;

  // workspace layout (halves first, 16B-aligned float region after)
  char* ws = (char*)d_ws;
  _Float16* wfrag = (_Float16*)ws;     // 12288
  _Float16* l1f = wfrag + 12288;       // 4096
  _Float16* l2f = l1f + 4096;          // 4096
  _Float16* fcf = l2f + 4096;          // 1024  -> total 21504 halves = 43008 B
  float* hbuf = (float*)(ws + 43008);  // NN*64
  float* hw = hbuf + NN * 64;          // NN*64
  float* dinv = hw + NN * 64;          // NN
  int* cnt = (int*)(dinv + NN);        // NN
  int* row_start = cnt + NN;           // NN+1
  int* cursor = row_start + NN + 1;    // NN
  int* csr_src = cursor + NN;          // EE
  int* part = csr_src + EE;            // 128

  const int* esrc = edge_index;
  const int* edst = edge_index + EE;

  hipMemsetAsync(cnt, 0, NN * sizeof(int), stream);
  // weight fragments (B-operands): w_hh is [192x64] -> 12 nf tiles
  build_frag_kernel<<<48, 256, 0, stream>>>(w_hh, wfrag, 192, 12);
  build_frag_kernel<<<16, 256, 0, stream>>>(gc1_w, l1f, 64, 4);
  build_frag_kernel<<<16, 256, 0, stream>>>(gc2_w, l2f, 64, 4);
  build_frag_kernel<<<4, 256, 0, stream>>>(fc_w, fcf, HORZ, 1);

  gru_kernel<<<(NN + 255) / 256, 1024, 0, stream>>>(x, w_ih, b_ih, b_hh, wfrag, hbuf);

  count_kernel<<<(EE / 4 + 255) / 256, 256, 0, stream>>>(edst, cnt);
  dinv_kernel<<<(NN + 255) / 256, 256, 0, stream>>>(cnt, dinv);
  scan1_kernel<<<NPB, 512, 0, stream>>>(cnt, part);
  scan2_kernel<<<1, 128, 0, stream>>>(part);
  scan3_kernel<<<NPB, 512, 0, stream>>>(cnt, part, row_start, cursor);
  scatter_kernel<<<(EE + 255) / 256, 256, 0, stream>>>(esrc, edst, cursor, csr_src);

  linear_mfma_kernel<<<(NN + 63) / 64, 256, 0, stream>>>(hbuf, l1f, dinv, hw);
  agg_kernel<<<(NN + 3) / 4, 256, 0, stream>>>(hw, dinv, row_start, csr_src, gc1_b, hbuf);
  linear_mfma_kernel<<<(NN + 63) / 64, 256, 0, stream>>>(hbuf, l2f, dinv, hw);
  agg_kernel<<<(NN + 3) / 4, 256, 0, stream>>>(hw, dinv, row_start, csr_src, gc2_b, hbuf);
  fc_mfma_kernel<<<(NN + 63) / 64, 256, 0, stream>>>(hbuf, fcf, fc_b, out);
}

// Round 3
// 407.679 us; speedup vs baseline: 1.9594x; 1.1701x over previous
//
#include <hip/hip_runtime.h>

#define NN 50000
#define TT 24
#define HH 64
#define HORZ 12
#define EE 1600000
#define NPB 98  // (NN+511)/512 scan blocks

typedef __attribute__((ext_vector_type(8))) _Float16 f16x8;
typedef __attribute__((ext_vector_type(4))) float f32x4;

__device__ __forceinline__ float sigm(float x) {
  return __builtin_amdgcn_rcpf(1.f + __expf(-x));
}
__device__ __forceinline__ float tanh_f(float x) {
  return 1.f - 2.f * __builtin_amdgcn_rcpf(1.f + __expf(2.f * x));
}

// ---------- build fp16 MFMA B-fragments for a [rows x 64] weight (out = h @ W^T) ----------
// layout: [nf][kf(2)][lane(64)][8];  B[k][col] = W[col][k], col = 16*nf + (l&15), k = 32*kf + 8*(l>>4) + j
__global__ void build_frag_kernel(const float* __restrict__ W, _Float16* __restrict__ frag,
                                  int rows, int nfr) {
  int idx = blockIdx.x * 256 + threadIdx.x;
  if (idx >= nfr * 1024) return;
  int j = idx & 7;
  int l = (idx >> 3) & 63;
  int kf = (idx >> 9) & 1;
  int nf = idx >> 10;
  int col = 16 * nf + (l & 15);
  int k = 32 * kf + 8 * (l >> 4) + j;
  frag[idx] = (col < rows) ? (_Float16)W[col * 64 + k] : (_Float16)0.f;
}

// ---------- MFMA GRU, gate-quarter split: block = 4 waves share 16 nodes ----------
// wave w computes gate dims [16w,16w+16) of r,z,n (nf tiles w, 4+w, 8+w).
// B-frags live in registers (loaded from global); only h bounces through 2.3KB LDS.
__global__ __launch_bounds__(256, 6) void gru_kernel(
    const float* __restrict__ x, const float* __restrict__ w_ih,
    const float* __restrict__ b_ih, const float* __restrict__ b_hh,
    const _Float16* __restrict__ wfrag, _Float16* __restrict__ hout) {
  __shared__ __align__(16) _Float16 sh[16][72];  // [node][dim], 144B row stride

  const int tid = threadIdx.x;
  const int lane = tid & 63;
  const int w = tid >> 6;   // gate quarter 0..3
  const int c = lane & 15;  // A-read: node row; D: gate dim within tile
  const int q = lane >> 4;
  const int d = 16 * w + c;  // owned gate dim 0..63

  // B-fragments for nf tiles {w, 4+w, 8+w}, kf 0..1  (24 VGPR)
  f16x8 Br0 = *(const f16x8*)&wfrag[(((w)*2 + 0) * 64 + lane) * 8];
  f16x8 Br1 = *(const f16x8*)&wfrag[(((w)*2 + 1) * 64 + lane) * 8];
  f16x8 Bz0 = *(const f16x8*)&wfrag[(((4 + w) * 2 + 0) * 64 + lane) * 8];
  f16x8 Bz1 = *(const f16x8*)&wfrag[(((4 + w) * 2 + 1) * 64 + lane) * 8];
  f16x8 Bn0 = *(const f16x8*)&wfrag[(((8 + w) * 2 + 0) * 64 + lane) * 8];
  f16x8 Bn1 = *(const f16x8*)&wfrag[(((8 + w) * 2 + 1) * 64 + lane) * 8];

  const float wir = w_ih[d], wiz = w_ih[64 + d], win = w_ih[128 + d];
  const float arb = b_ih[d] + b_hh[d];
  const float azb = b_ih[64 + d] + b_hh[64 + d];
  const float bin = b_ih[128 + d];
  const float bhn = b_hh[128 + d];

  const int base = blockIdx.x * 16;  // 3125 blocks * 16 nodes = 50000 exactly
  const float* xb = x + base * TT;

  float hreg[4] = {0.f, 0.f, 0.f, 0.f};  // h[node 4q+r][dim d], fp32 recurrence

#pragma unroll 1
  for (int t = 0; t < TT; ++t) {
    f32x4 ar = (f32x4){arb, arb, arb, arb};
    f32x4 az = (f32x4){azb, azb, azb, azb};
    f32x4 an = (f32x4){bhn, bhn, bhn, bhn};
    if (t > 0) {
      f16x8 a0 = *(const f16x8*)&sh[c][8 * q];
      f16x8 a1 = *(const f16x8*)&sh[c][32 + 8 * q];
      ar = __builtin_amdgcn_mfma_f32_16x16x32_f16(a0, Br0, ar, 0, 0, 0);
      az = __builtin_amdgcn_mfma_f32_16x16x32_f16(a0, Bz0, az, 0, 0, 0);
      an = __builtin_amdgcn_mfma_f32_16x16x32_f16(a0, Bn0, an, 0, 0, 0);
      ar = __builtin_amdgcn_mfma_f32_16x16x32_f16(a1, Br1, ar, 0, 0, 0);
      az = __builtin_amdgcn_mfma_f32_16x16x32_f16(a1, Bz1, az, 0, 0, 0);
      an = __builtin_amdgcn_mfma_f32_16x16x32_f16(a1, Bn1, an, 0, 0, 0);
    }
    float hn[4];
#pragma unroll
    for (int r = 0; r < 4; ++r) {
      float xt = xb[(4 * q + r) * TT + t];
      float rg = sigm(xt * wir + ar[r]);
      float zg = sigm(xt * wiz + az[r]);
      float nn = tanh_f(rg * an[r] + (xt * win + bin));
      hn[r] = nn + zg * (hreg[r] - nn);
      hreg[r] = hn[r];
    }
    __syncthreads();  // prior step's A-frag reads complete before overwrite
#pragma unroll
    for (int r = 0; r < 4; ++r) sh[4 * q + r][d] = (_Float16)hn[r];
    __syncthreads();  // h visible for next step's A-frag reads
  }

#pragma unroll
  for (int r = 0; r < 4; ++r) hout[(base + 4 * q + r) * 64 + d] = (_Float16)hreg[r];
}

// ---------- degree histogram (int4) ----------
__global__ void count_kernel(const int* __restrict__ dst, int* __restrict__ cnt) {
  int i = blockIdx.x * 256 + threadIdx.x;
  int b = i * 4;
  if (b + 3 < EE) {
    int4 d = *(const int4*)&dst[b];
    atomicAdd(&cnt[d.x], 1);
    atomicAdd(&cnt[d.y], 1);
    atomicAdd(&cnt[d.z], 1);
    atomicAdd(&cnt[d.w], 1);
  } else {
    for (int k = b; k < EE; ++k) atomicAdd(&cnt[dst[k]], 1);
  }
}

// ---------- scan (3-phase) for CSR row offsets ----------
__global__ void scan1_kernel(const int* __restrict__ cnt, int* __restrict__ part) {
  __shared__ int s[512];
  int i = blockIdx.x * 512 + threadIdx.x;
  s[threadIdx.x] = (i < NN) ? cnt[i] : 0;
  __syncthreads();
  for (int off = 256; off > 0; off >>= 1) {
    if (threadIdx.x < off) s[threadIdx.x] += s[threadIdx.x + off];
    __syncthreads();
  }
  if (threadIdx.x == 0) part[blockIdx.x] = s[0];
}

__global__ void scan2_kernel(int* __restrict__ part) {
  __shared__ int s[128];
  int t = threadIdx.x;
  int v = (t < NPB) ? part[t] : 0;
  s[t] = v;
  __syncthreads();
  for (int off = 1; off < 128; off <<= 1) {
    int a = s[t];
    int b = (t >= off) ? s[t - off] : 0;
    __syncthreads();
    s[t] = a + b;
    __syncthreads();
  }
  if (t < NPB) part[t] = s[t] - v;  // exclusive
}

__global__ void scan3_kernel(const int* __restrict__ cnt, const int* __restrict__ part,
                             int* __restrict__ row_start, int* __restrict__ cursor,
                             float* __restrict__ dinv) {
  __shared__ int s[2][512];
  int tid = threadIdx.x;
  int i = blockIdx.x * 512 + tid;
  int v = (i < NN) ? cnt[i] : 0;
  s[0][tid] = v;
  __syncthreads();
  int cur = 0;
  for (int off = 1; off < 512; off <<= 1) {
    int nxt = cur ^ 1;
    int val = s[cur][tid] + ((tid >= off) ? s[cur][tid - off] : 0);
    s[nxt][tid] = val;
    __syncthreads();
    cur = nxt;
  }
  int excl = s[cur][tid] - v;
  if (i < NN) {
    int rs = part[blockIdx.x] + excl;
    row_start[i] = rs;
    cursor[i] = rs;
    dinv[i] = rsqrtf((float)(v + 1));  // +1 self loop
  }
  if (i == 0) row_start[NN] = EE;
}

__global__ void scatter_kernel(const int* __restrict__ src, const int* __restrict__ dst,
                               int* __restrict__ cursor, int* __restrict__ csr_src) {
  int i = blockIdx.x * 256 + threadIdx.x;
  if (i < EE) {
    int p = atomicAdd(&cursor[dst[i]], 1);
    csr_src[p] = src[i];
  }
}

// ---------- MFMA linear: out[n] = f16( dinv[n] * (h[n] @ W^T) ), 64->64 ----------
__global__ __launch_bounds__(256) void linear_mfma_kernel(
    const _Float16* __restrict__ hin, const _Float16* __restrict__ frag,
    const float* __restrict__ dinv, _Float16* __restrict__ out) {
  const int tid = threadIdx.x;
  const int lane = tid & 63;
  const int w = tid >> 6;
  const int c = lane & 15;
  const int q = lane >> 4;
  int n0 = blockIdx.x * 64 + w * 16;
  int nA = n0 + c;
  int nc = nA < NN ? nA : NN - 1;  // clamp; garbage rows never stored
  const _Float16* hp = hin + nc * 64;

  f16x8 a0 = *(const f16x8*)&hp[8 * q];
  f16x8 a1 = *(const f16x8*)&hp[32 + 8 * q];
  f32x4 acc[4];
#pragma unroll
  for (int nf = 0; nf < 4; ++nf) acc[nf] = (f32x4){0.f, 0.f, 0.f, 0.f};
#pragma unroll
  for (int nf = 0; nf < 4; ++nf) {
    f16x8 b0 = *(const f16x8*)&frag[((nf * 2 + 0) * 64 + lane) * 8];
    acc[nf] = __builtin_amdgcn_mfma_f32_16x16x32_f16(a0, b0, acc[nf], 0, 0, 0);
  }
#pragma unroll
  for (int nf = 0; nf < 4; ++nf) {
    f16x8 b1 = *(const f16x8*)&frag[((nf * 2 + 1) * 64 + lane) * 8];
    acc[nf] = __builtin_amdgcn_mfma_f32_16x16x32_f16(a1, b1, acc[nf], 0, 0, 0);
  }
#pragma unroll
  for (int r = 0; r < 4; ++r) {
    int n = n0 + 4 * q + r;
    if (n < NN) {
      float dn = dinv[n];
#pragma unroll
      for (int nf = 0; nf < 4; ++nf)
        out[n * 64 + c + 16 * nf] = (_Float16)(acc[nf][r] * dn);
    }
  }
}

// ---------- CSR aggregation (pre-scaled f16 hw) + bias + relu; wave per node ----------
__global__ __launch_bounds__(256) void agg_kernel(
    const _Float16* __restrict__ hwp, const float* __restrict__ dinv,
    const int* __restrict__ row_start, const int* __restrict__ csr_src,
    const float* __restrict__ bias, _Float16* __restrict__ out) {
  int wid = blockIdx.x * 4 + (threadIdx.x >> 6);
  int lane = threadIdx.x & 63;
  if (wid >= NN) return;
  int e0 = row_start[wid], e1 = row_start[wid + 1];
  float a0 = (float)hwp[wid * 64 + lane];  // self loop (already dinv-scaled)
  float a1 = 0.f, a2 = 0.f, a3 = 0.f;
  int e = e0;
  for (; e + 4 <= e1; e += 4) {
    int s0 = csr_src[e], s1 = csr_src[e + 1], s2 = csr_src[e + 2], s3 = csr_src[e + 3];
    a0 += (float)hwp[s0 * 64 + lane];
    a1 += (float)hwp[s1 * 64 + lane];
    a2 += (float)hwp[s2 * 64 + lane];
    a3 += (float)hwp[s3 * 64 + lane];
  }
  for (; e < e1; ++e) a0 += (float)hwp[csr_src[e] * 64 + lane];
  float v = (a0 + a1 + a2 + a3) * dinv[wid] + bias[lane];
  out[wid * 64 + lane] = (_Float16)(v > 0.f ? v : 0.f);
}

// ---------- MFMA final FC (64 -> 12, padded to 16) ----------
__global__ __launch_bounds__(256) void fc_mfma_kernel(
    const _Float16* __restrict__ hin, const _Float16* __restrict__ frag,
    const float* __restrict__ bias, float* __restrict__ out) {
  const int tid = threadIdx.x;
  const int lane = tid & 63;
  const int w = tid >> 6;
  const int c = lane & 15;
  const int q = lane >> 4;
  int n0 = blockIdx.x * 64 + w * 16;
  int nA = n0 + c;
  int nc = nA < NN ? nA : NN - 1;
  const _Float16* hp = hin + nc * 64;

  f16x8 a0 = *(const f16x8*)&hp[8 * q];
  f16x8 a1 = *(const f16x8*)&hp[32 + 8 * q];
  float bc = (c < HORZ) ? bias[c] : 0.f;
  f32x4 acc = (f32x4){bc, bc, bc, bc};
  f16x8 b0 = *(const f16x8*)&frag[(0 * 64 + lane) * 8];
  f16x8 b1 = *(const f16x8*)&frag[(1 * 64 + lane) * 8];
  acc = __builtin_amdgcn_mfma_f32_16x16x32_f16(a0, b0, acc, 0, 0, 0);
  acc = __builtin_amdgcn_mfma_f32_16x16x32_f16(a1, b1, acc, 0, 0, 0);
  if (c < HORZ) {
#pragma unroll
    for (int r = 0; r < 4; ++r) {
      int n = n0 + 4 * q + r;
      if (n < NN) out[n * HORZ + c] = acc[r];
    }
  }
}

extern "C" void kernel_launch(void* const* d_in, const int* in_sizes, int n_in,
                              void* d_out, int out_size, void* d_ws, size_t ws_size,
                              hipStream_t stream) {
  (void)in_sizes; (void)n_in; (void)out_size; (void)ws_size;
  const float* x = (const float*)d_in[0];
  const int* edge_index = (const int*)d_in[1];
  const float* w_ih = (const float*)d_in[2];
  const float* w_hh = (const float*)d_in[3];
  const float* b_ih = (const float*)d_in[4];
  const float* b_hh = (const float*)d_in[5];
  const float* gc1_w = (const float*)d_in[6];
  const float* gc1_b = (const float*)d_in[7];
  const float* gc2_w = (const float*)d_in[8];
  const float* gc2_b = (const float*)d_in[9];
  const float* fc_w = (const float*)d_in[10];
  const float* fc_b = (const float*)d_in[11];
  float* out = (float*)d_out;

  // workspace layout
  char* ws = (char*)d_ws;
  _Float16* wfrag = (_Float16*)ws;           // 12288 halves
  _Float16* l1f = wfrag + 12288;             // 4096
  _Float16* l2f = l1f + 4096;                // 4096
  _Float16* fcf = l2f + 4096;                // 1024 -> 21504 halves = 43008 B
  _Float16* hbuf = (_Float16*)(ws + 43008);  // NN*64 f16 (gru out / agg out)
  _Float16* hw = hbuf + NN * 64;             // NN*64 f16 (linear out, dinv-scaled)
  float* dinv = (float*)(hw + NN * 64);      // NN f32
  int* cnt = (int*)(dinv + NN);              // NN
  int* row_start = cnt + NN;                 // NN+1
  int* cursor = row_start + NN + 1;          // NN
  int* csr_src = cursor + NN;                // EE
  int* part = csr_src + EE;                  // 128

  const int* esrc = edge_index;
  const int* edst = edge_index + EE;

  hipMemsetAsync(cnt, 0, NN * sizeof(int), stream);
  build_frag_kernel<<<48, 256, 0, stream>>>(w_hh, wfrag, 192, 12);
  build_frag_kernel<<<16, 256, 0, stream>>>(gc1_w, l1f, 64, 4);
  build_frag_kernel<<<16, 256, 0, stream>>>(gc2_w, l2f, 64, 4);
  build_frag_kernel<<<4, 256, 0, stream>>>(fc_w, fcf, HORZ, 1);

  gru_kernel<<<NN / 16, 256, 0, stream>>>(x, w_ih, b_ih, b_hh, wfrag, hbuf);

  count_kernel<<<(EE / 4 + 255) / 256, 256, 0, stream>>>(edst, cnt);
  scan1_kernel<<<NPB, 512, 0, stream>>>(cnt, part);
  scan2_kernel<<<1, 128, 0, stream>>>(part);
  scan3_kernel<<<NPB, 512, 0, stream>>>(cnt, part, row_start, cursor, dinv);
  scatter_kernel<<<(EE + 255) / 256, 256, 0, stream>>>(esrc, edst, cursor, csr_src);

  linear_mfma_kernel<<<(NN + 63) / 64, 256, 0, stream>>>(hbuf, l1f, dinv, hw);
  agg_kernel<<<(NN + 3) / 4, 256, 0, stream>>>(hw, dinv, row_start, csr_src, gc1_b, hbuf);
  linear_mfma_kernel<<<(NN + 63) / 64, 256, 0, stream>>>(hbuf, l2f, dinv, hw);
  agg_kernel<<<(NN + 3) / 4, 256, 0, stream>>>(hw, dinv, row_start, csr_src, gc2_b, hbuf);
  fc_mfma_kernel<<<(NN + 63) / 64, 256, 0, stream>>>(hbuf, fcf, fc_b, out);
}